// Round 7
// baseline (696.757 us; speedup 1.0000x reference)
//
#include <hip/hip_runtime.h>
#include <cstdint>
#include <cstddef>

#define NEG_K 50
#define POSCAP 128
#define CANDCAP 2048
#define FBINS 4096
#define BNDCAP 192
#define TSEL 2.75f
#define TSCALE 819.2f   // FBINS / 5.0 ; covers (2.75, 7.75]

typedef __attribute__((ext_vector_type(8))) short bf16x8;
typedef __attribute__((ext_vector_type(4))) float f32x4;

// fp32 -> bf16 round-to-nearest-even (finite inputs)
__device__ __forceinline__ unsigned f2b(float x) {
    unsigned u = __float_as_uint(x);
    return (u + 0x7FFFu + ((u >> 16) & 1u)) >> 16;
}
__device__ __forceinline__ uint4 pack8(float4 a, float4 b) {
    uint4 r;
    r.x = f2b(a.x) | (f2b(a.y) << 16);
    r.y = f2b(a.z) | (f2b(a.w) << 16);
    r.z = f2b(b.x) | (f2b(b.y) << 16);
    r.w = f2b(b.z) | (f2b(b.w) << 16);
    return r;
}
__device__ __forceinline__ int fbin(float s) {
    int b = (int)((s - TSEL) * TSCALE);
    return b < 0 ? 0 : (b > FBINS - 1 ? FBINS - 1 : b);
}

// F (fp32, 256x256) -> Fb (bf16). 32 blocks x 256 thr x 8 elems.
__global__ __launch_bounds__(256) void convF_kernel(const float* __restrict__ F,
                                                    unsigned short* __restrict__ Fb) {
    int i = (blockIdx.x * 256 + threadIdx.x) * 8;
    float4 a = *(const float4*)(F + i);
    float4 b = *(const float4*)(F + i + 4);
    *(uint4*)(Fb + i) = pack8(a, b);
}

__global__ __launch_bounds__(256) void setup_kernel(const int* __restrict__ il,
                                                    const int* __restrict__ ipi,
                                                    const int* __restrict__ apl,
                                                    int B, int* __restrict__ batch_lbl,
                                                    int* __restrict__ posn,
                                                    int* __restrict__ candn,
                                                    float* __restrict__ out) {
    int i = threadIdx.x;
    if (i == 0) out[0] = 0.0f;
    if (i < B) {
        batch_lbl[i] = apl[ipi[il[i]]];
        posn[i] = 0;
        candn[i] = 0;
    }
}

// Fused GEMM + classify. BM=256 (all rows), BN=64, BK=64, 4 waves (each 64rx64c).
// A (bf16) staged via global_load_lds with inverse-swizzled source; B (fp32)
// converted on the fly, swizzled ds_write. Swizzle: 16B-chunk ^ (row&7).
__global__ __launch_bounds__(256) void gemm_fused(const unsigned short* __restrict__ Fb,
                                                  const float* __restrict__ Pm,
                                                  const int* __restrict__ apl,
                                                  const int* __restrict__ batch_lbl,
                                                  int* __restrict__ posn,
                                                  float* __restrict__ posv,
                                                  int* __restrict__ posi,
                                                  int* __restrict__ candn,
                                                  float* __restrict__ cand,
                                                  int P) {
    __shared__ __align__(16) char As[32 * 1024];   // [256 rows][64 k] bf16, swizzled
    __shared__ __align__(16) char Bs[8 * 1024];    // [64 rows][64 k] bf16, swizzled

    int t = threadIdx.x;
    int l = t & 63;
    int w = t >> 6;
    int p0 = blockIdx.x * 64;

    f32x4 acc[4][4];
#pragma unroll
    for (int m = 0; m < 4; m++)
#pragma unroll
        for (int n = 0; n < 4; n++) acc[m][n] = (f32x4){0.f, 0.f, 0.f, 0.f};

    // B staging geometry (per thread: one row-chunk pair)
    int rowb = t >> 2;            // 0..63
    int kq0  = (t & 3) * 2;       // chunk pair: {0,2,4,6}
    int gp   = p0 + rowb; if (gp >= P) gp = P - 1;
    const float* pmrow = Pm + (size_t)gp * 256;
    int ob0 = rowb * 128 + ((kq0)     ^ (rowb & 7)) * 16;
    int ob1 = rowb * 128 + ((kq0 + 1) ^ (rowb & 7)) * 16;

    for (int kk = 0; kk < 256; kk += 64) {
        // ---- A: 8 x global_load_lds per wave (1 KiB each: 8 rows x 128 B) ----
#pragma unroll
        for (int i = 0; i < 8; i++) {
            int row = (w * 8 + i) * 8 + (l >> 3);
            int srckq = (l & 7) ^ (row & 7);          // inverse swizzle on source
            const unsigned short* src = Fb + row * 256 + kk + srckq * 8;
            __builtin_amdgcn_global_load_lds(
                (const __attribute__((address_space(1))) unsigned int*)src,
                (__attribute__((address_space(3))) unsigned int*)(As + (w * 8 + i) * 1024),
                16, 0, 0);
        }
        // ---- B: load fp32, convert RNE, swizzled ds_write ----
        const float* ps = pmrow + kk + kq0 * 8;
        float4 b0 = *(const float4*)(ps);
        float4 b1 = *(const float4*)(ps + 4);
        float4 b2 = *(const float4*)(ps + 8);
        float4 b3 = *(const float4*)(ps + 12);
        *(uint4*)(Bs + ob0) = pack8(b0, b1);
        *(uint4*)(Bs + ob1) = pack8(b2, b3);
        __syncthreads();

#pragma unroll
        for (int ks = 0; ks < 2; ks++) {
            int kq = ks * 4 + (l >> 4);
            bf16x8 af[4], bfr[4];
#pragma unroll
            for (int m = 0; m < 4; m++) {
                int ra = w * 64 + m * 16 + (l & 15);
                af[m] = *(const bf16x8*)(As + ra * 128 + ((kq ^ (ra & 7)) * 16));
            }
#pragma unroll
            for (int n = 0; n < 4; n++) {
                int rb = n * 16 + (l & 15);
                bfr[n] = *(const bf16x8*)(Bs + rb * 128 + ((kq ^ (rb & 7)) * 16));
            }
#pragma unroll
            for (int m = 0; m < 4; m++)
#pragma unroll
                for (int n = 0; n < 4; n++)
                    acc[m][n] = __builtin_amdgcn_mfma_f32_16x16x32_bf16(af[m], bfr[n], acc[m][n], 0, 0, 0);
        }
        __syncthreads();
    }

    // ---- epilogue: classify into per-row positive / candidate lists ----
    int lblv[4]; bool pok[4];
#pragma unroll
    for (int n = 0; n < 4; n++) {
        int p = p0 + n * 16 + (l & 15);
        pok[n] = (p < P);
        lblv[n] = pok[n] ? apl[p] : -1;
    }
#pragma unroll
    for (int m = 0; m < 4; m++) {
#pragma unroll
        for (int j = 0; j < 4; j++) {
            int g = w * 64 + m * 16 + ((l >> 4) << 2) + j;
            int ml = batch_lbl[g];
#pragma unroll
            for (int n = 0; n < 4; n++) {
                if (!pok[n]) continue;
                float s = acc[m][n][j] * 20.0f;
                if (lblv[n] == ml) {
                    int idx = atomicAdd(&posn[g], 1);
                    if (idx < POSCAP) {
                        posv[g * POSCAP + idx] = s;
                        posi[g * POSCAP + idx] = p0 + n * 16 + (l & 15);
                    }
                } else if (s > TSEL) {
                    int idx = atomicAdd(&candn[g], 1);
                    if (idx < CANDCAP) cand[(size_t)g * CANDCAP + idx] = s;
                }
            }
        }
    }
}

// One block per row: exact top-m among candidates (linear bins), LSE, loss.
__global__ __launch_bounds__(256) void final_kernel(const int* __restrict__ posn,
                                                    const float* __restrict__ posv,
                                                    const int* __restrict__ posi,
                                                    const int* __restrict__ candn,
                                                    const float* __restrict__ cand,
                                                    float* __restrict__ out, int B) {
    __shared__ unsigned hist[FBINS];
    __shared__ unsigned ssum[256];
    __shared__ float red[256];
    __shared__ float bnd[BNDCAP];
    __shared__ float pv[POSCAP];
    __shared__ int pidx[POSCAP];
    __shared__ int sh_bstar, sh_cumabove, sh_bndn;
    __shared__ float w_bsum, w_ps, w_pe;

    int tid = threadIdx.x;
    int g = blockIdx.x;
    int pn = posn[g];
    int pcap = min(pn, POSCAP);
    int q = min(pn, NEG_K);
    int m = NEG_K - q;
    int cn = min(candn[g], CANDCAP);
    const float* crow = cand + (size_t)g * CANDCAP;

    for (int b = tid; b < FBINS; b += 256) hist[b] = 0u;
    if (tid == 0) {
        sh_bstar = FBINS; sh_cumabove = 0; sh_bndn = 0;
        w_bsum = 0.0f; w_ps = 0.0f; w_pe = 0.0f;
    }
    __syncthreads();

    if (m > 0) {
        for (int c = tid; c < cn; c += 256)
            atomicAdd(&hist[fbin(crow[c])], 1u);
    }
    __syncthreads();

    unsigned sum16 = 0;
    int base = tid * (FBINS / 256);
#pragma unroll
    for (int b = 0; b < FBINS / 256; b++) sum16 += hist[base + b];
    ssum[tid] = sum16;
    __syncthreads();
    for (int off = 1; off < 256; off <<= 1) {
        unsigned v = (tid + off < 256) ? ssum[tid + off] : 0u;
        __syncthreads();
        ssum[tid] += v;
        __syncthreads();
    }
    unsigned total = ssum[0];
    unsigned target = (m > 0) ? min(total, (unsigned)m) : 0u;
    if (target > 0) {
        unsigned above = (tid < 255) ? ssum[tid + 1] : 0u;
        if (ssum[tid] >= target && above < target) {
            unsigned cum = above;
            for (int b = base + FBINS / 256 - 1; b >= base; b--) {
                unsigned nc = cum + hist[b];
                if (nc >= target) { sh_bstar = b; sh_cumabove = (int)cum; break; }
                cum = nc;
            }
        }
    }
    __syncthreads();
    int bstar = sh_bstar;
    int cumabove = sh_cumabove;

    float se = 0.0f;
    if (m > 0) {
        for (int c = tid; c < cn; c += 256) {
            float s = crow[c];
            int bin = fbin(s);
            if (bin > bstar) se += expf(s - 20.0f);
            else if (bin == bstar) {
                int n = atomicAdd(&sh_bndn, 1);
                if (n < BNDCAP) bnd[n] = s;
            }
        }
    }
    red[tid] = se;
    for (int c = tid; c < pcap; c += 256) {
        pv[c] = posv[g * POSCAP + c];
        pidx[c] = posi[g * POSCAP + c];
    }
    __syncthreads();
    for (int off = 128; off > 0; off >>= 1) {
        if (tid < off) red[tid] += red[tid + off];
        __syncthreads();
    }
    float negexp_above = red[0];
    __syncthreads();

    float psum_p = 0.0f, pexp_p = 0.0f;
    if (pn <= NEG_K) {
        for (int c = tid; c < pcap; c += 256) {
            float v = pv[c];
            psum_p += v;
            pexp_p += expf(v - 20.0f);
        }
    }
    red[tid] = psum_p;
    __syncthreads();
    for (int off = 128; off > 0; off >>= 1) { if (tid < off) red[tid] += red[tid + off]; __syncthreads(); }
    float possum = red[0];
    __syncthreads();
    red[tid] = pexp_p;
    __syncthreads();
    for (int off = 128; off > 0; off >>= 1) { if (tid < off) red[tid] += red[tid + off]; __syncthreads(); }
    float posexp = red[0];
    __syncthreads();

    if (tid < 64) {
        int lane = tid;
        float bsum = 0.0f, ps = 0.0f, pe = 0.0f;
        if (m > 0) {
            int bn = min(sh_bndn, BNDCAP);
            int r = m - cumabove;
            if (r > bn) r = bn;
            for (int it = 0; it < r; it++) {
                float mx = -3.0e38f; int mi = -1;
                for (int c = lane; c < bn; c += 64) {
                    float v = bnd[c];
                    if (v > mx) { mx = v; mi = c; }
                }
#pragma unroll
                for (int off = 32; off > 0; off >>= 1) {
                    float ox = __shfl_xor(mx, off);
                    int oi = __shfl_xor(mi, off);
                    if (ox > mx || (ox == mx && oi >= 0 && (mi < 0 || oi < mi))) { mx = ox; mi = oi; }
                }
                if (lane == 0) {
                    bsum += expf(mx - 20.0f);
                    if (mi >= 0) bnd[mi] = -3.0e38f;
                }
            }
        }
        if (pn > NEG_K) {
            for (int it = 0; it < NEG_K; it++) {
                int mn = 0x7fffffff; int mc = -1;
                for (int c = lane; c < pcap; c += 64) {
                    int ix = pidx[c];
                    if (ix < mn) { mn = ix; mc = c; }
                }
#pragma unroll
                for (int off = 32; off > 0; off >>= 1) {
                    int on = __shfl_xor(mn, off);
                    int oc = __shfl_xor(mc, off);
                    if (on < mn) { mn = on; mc = oc; }
                }
                if (lane == 0 && mc >= 0) {
                    float v = pv[mc];
                    ps += v;
                    pe += expf(v - 20.0f);
                    pidx[mc] = 0x7fffffff;
                }
            }
        }
        if (lane == 0) { w_bsum = bsum; w_ps = ps; w_pe = pe; }
    }
    __syncthreads();

    if (tid == 0) {
        float pos_e = (pn <= NEG_K) ? posexp : w_pe;
        float pos_s = (pn <= NEG_K) ? possum : w_ps;
        float totexp = negexp_above + w_bsum + pos_e;
        float lse = 20.0f + logf(totexp);
        float loss = ((float)q * lse - pos_s) / (float)max(pn, 1);
        atomicAdd(out, loss / (float)B);
    }
}

extern "C" void kernel_launch(void* const* d_in, const int* in_sizes, int n_in,
                              void* d_out, int out_size, void* d_ws, size_t ws_size,
                              hipStream_t stream) {
    const float* F  = (const float*)d_in[0];
    const int* il   = (const int*)d_in[1];
    const float* Pm = (const float*)d_in[2];
    const int* ipi  = (const int*)d_in[3];
    const int* apl  = (const int*)d_in[4];
    float* out = (float*)d_out;

    const int D = 256;
    const int B = in_sizes[0] / D;      // 256
    const int P = in_sizes[2] / D;      // 100000

    char* ws = (char*)d_ws;
    unsigned short* Fb = (unsigned short*)ws;                 // 128 KiB
    int* batch_lbl = (int*)(ws + 131072);
    int* posn      = (int*)(ws + 131072 + 1024);
    int* candn     = (int*)(ws + 131072 + 2048);
    float* posv    = (float*)(ws + 131072 + 4096);
    int* posi      = (int*)(ws + 131072 + 4096 + 256 * POSCAP * 4);
    float* cand    = (float*)(ws + 131072 + 4096 + 2 * 256 * POSCAP * 4);

    convF_kernel<<<(B * D) / (256 * 8), 256, 0, stream>>>(F, Fb);
    setup_kernel<<<1, 256, 0, stream>>>(il, ipi, apl, B, batch_lbl, posn, candn, out);

    int nb = (P + 63) / 64;
    gemm_fused<<<nb, 256, 0, stream>>>(Fb, Pm, apl, batch_lbl,
                                       posn, posv, posi, candn, cand, P);
    final_kernel<<<B, 256, 0, stream>>>(posn, posv, posi, candn, cand, out, B);
}

// Round 11
// 256.311 us; speedup vs baseline: 2.7184x; 2.7184x over previous
//
#include <hip/hip_runtime.h>
#include <cstdint>
#include <cstddef>

#define NEG_K 50
#define POSCAP 128
#define NSLOT 12          // candidate slots per (block, row)
#define FBINS 4096
#define BNDCAP 192
#define TSEL 2.75f
#define TSCALE 819.2f     // FBINS / 5.0 ; bins cover (2.75, 7.75], top bin clamps

typedef __attribute__((ext_vector_type(8))) short bf16x8;
typedef __attribute__((ext_vector_type(4))) float f32x4;

// fp32 -> bf16 round-to-nearest-even (finite inputs)
__device__ __forceinline__ unsigned f2b(float x) {
    unsigned u = __float_as_uint(x);
    return (u + 0x7FFFu + ((u >> 16) & 1u)) >> 16;
}
__device__ __forceinline__ uint4 pack8(float4 a, float4 b) {
    uint4 r;
    r.x = f2b(a.x) | (f2b(a.y) << 16);
    r.y = f2b(a.z) | (f2b(a.w) << 16);
    r.z = f2b(b.x) | (f2b(b.y) << 16);
    r.w = f2b(b.z) | (f2b(b.w) << 16);
    return r;
}
__device__ __forceinline__ int fbin(float s) {
    int b = (int)((s - TSEL) * TSCALE);
    return b < 0 ? 0 : (b > FBINS - 1 ? FBINS - 1 : b);
}

// F (fp32, 256x256) -> Fb (bf16). 32 blocks x 256 thr x 8 elems.
__global__ __launch_bounds__(256) void convF_kernel(const float* __restrict__ F,
                                                    unsigned short* __restrict__ Fb) {
    int i = (blockIdx.x * 256 + threadIdx.x) * 8;
    float4 a = *(const float4*)(F + i);
    float4 b = *(const float4*)(F + i + 4);
    *(uint4*)(Fb + i) = pack8(a, b);
}

__global__ __launch_bounds__(256) void setup_kernel(const int* __restrict__ il,
                                                    const int* __restrict__ ipi,
                                                    const int* __restrict__ apl,
                                                    int B, int* __restrict__ batch_lbl,
                                                    int* __restrict__ posn,
                                                    float* __restrict__ out) {
    int i = threadIdx.x;
    if (i == 0) out[0] = 0.0f;
    if (i < B) {
        batch_lbl[i] = apl[ipi[il[i]]];
        posn[i] = 0;
    }
}

// Fused GEMM + classify. BM=256 (all rows), BN=64, BK=64, 4 waves (each 64rx64c).
// A (bf16) staged via global_load_lds with inverse-swizzled source; B (fp32)
// converted on the fly, swizzled ds_write. Swizzle: 16B-chunk ^ (row&7).
// Epilogue: block-local LDS compaction -> fixed sentinel-padded slot writes
// (NO global atomics for candidates -> no cross-XCD same-address serialization).
__global__ __launch_bounds__(256) void gemm_fused(const unsigned short* __restrict__ Fb,
                                                  const float* __restrict__ Pm,
                                                  const int* __restrict__ apl,
                                                  const int* __restrict__ batch_lbl,
                                                  int* __restrict__ posn,
                                                  float* __restrict__ posv,
                                                  int* __restrict__ posi,
                                                  float* __restrict__ slots,
                                                  int P) {
    __shared__ __align__(16) char As[32 * 1024];   // [256 rows][64 k] bf16, swizzled
    __shared__ __align__(16) char Bs[8 * 1024];    // [64 rows][64 k] bf16, swizzled

    int t = threadIdx.x;
    int l = t & 63;
    int w = t >> 6;
    int p0 = blockIdx.x * 64;

    f32x4 acc[4][4];
#pragma unroll
    for (int m = 0; m < 4; m++)
#pragma unroll
        for (int n = 0; n < 4; n++) acc[m][n] = (f32x4){0.f, 0.f, 0.f, 0.f};

    // B staging geometry (per thread: one row-chunk pair)
    int rowb = t >> 2;            // 0..63
    int kq0  = (t & 3) * 2;       // chunk pair: {0,2,4,6}
    int gp   = p0 + rowb; if (gp >= P) gp = P - 1;
    const float* pmrow = Pm + (size_t)gp * 256;
    int ob0 = rowb * 128 + ((kq0)     ^ (rowb & 7)) * 16;
    int ob1 = rowb * 128 + ((kq0 + 1) ^ (rowb & 7)) * 16;

    for (int kk = 0; kk < 256; kk += 64) {
        // ---- A: 8 x global_load_lds per wave (1 KiB each: 8 rows x 128 B) ----
#pragma unroll
        for (int i = 0; i < 8; i++) {
            int row = (w * 8 + i) * 8 + (l >> 3);
            int srckq = (l & 7) ^ (row & 7);          // inverse swizzle on source
            const unsigned short* src = Fb + row * 256 + kk + srckq * 8;
            __builtin_amdgcn_global_load_lds(
                (const __attribute__((address_space(1))) unsigned int*)src,
                (__attribute__((address_space(3))) unsigned int*)(As + (w * 8 + i) * 1024),
                16, 0, 0);
        }
        // ---- B: load fp32, convert RNE, swizzled ds_write ----
        const float* ps = pmrow + kk + kq0 * 8;
        float4 b0 = *(const float4*)(ps);
        float4 b1 = *(const float4*)(ps + 4);
        float4 b2 = *(const float4*)(ps + 8);
        float4 b3 = *(const float4*)(ps + 12);
        *(uint4*)(Bs + ob0) = pack8(b0, b1);
        *(uint4*)(Bs + ob1) = pack8(b2, b3);
        __syncthreads();

#pragma unroll
        for (int ks = 0; ks < 2; ks++) {
            int kq = ks * 4 + (l >> 4);
            bf16x8 af[4], bfr[4];
#pragma unroll
            for (int m = 0; m < 4; m++) {
                int ra = w * 64 + m * 16 + (l & 15);
                af[m] = *(const bf16x8*)(As + ra * 128 + ((kq ^ (ra & 7)) * 16));
            }
#pragma unroll
            for (int n = 0; n < 4; n++) {
                int rb = n * 16 + (l & 15);
                bfr[n] = *(const bf16x8*)(Bs + rb * 128 + ((kq ^ (rb & 7)) * 16));
            }
#pragma unroll
            for (int m = 0; m < 4; m++)
#pragma unroll
                for (int n = 0; n < 4; n++)
                    acc[m][n] = __builtin_amdgcn_mfma_f32_16x16x32_bf16(af[m], bfr[n], acc[m][n], 0, 0, 0);
        }
        __syncthreads();
    }

    // ---- epilogue: LDS slot compaction (reuse As/Bs storage) ----
    float* slotv = (float*)As;     // 256 * NSLOT floats = 12 KiB
    int*   scnt  = (int*)Bs;       // 256 ints = 1 KiB
    for (int i = t; i < 256 * NSLOT; i += 256) slotv[i] = -3.0e38f;
    scnt[t] = 0;
    __syncthreads();

    int lblv[4]; bool pok[4];
#pragma unroll
    for (int n = 0; n < 4; n++) {
        int p = p0 + n * 16 + (l & 15);
        pok[n] = (p < P);
        lblv[n] = pok[n] ? apl[p] : -1;
    }
#pragma unroll
    for (int m = 0; m < 4; m++) {
#pragma unroll
        for (int j = 0; j < 4; j++) {
            int g = w * 64 + m * 16 + ((l >> 4) << 2) + j;
            int ml = batch_lbl[g];
#pragma unroll
            for (int n = 0; n < 4; n++) {
                if (!pok[n]) continue;
                float s = acc[m][n][j] * 20.0f;
                if (lblv[n] == ml) {
                    int idx = atomicAdd(&posn[g], 1);   // rare (~10/row total)
                    if (idx < POSCAP) {
                        posv[g * POSCAP + idx] = s;
                        posi[g * POSCAP + idx] = p0 + n * 16 + (l & 15);
                    }
                } else if (s > TSEL) {
                    int idx = atomicAdd(&scnt[g], 1);   // LDS atomic, block-local
                    if (idx < NSLOT) slotv[g * NSLOT + idx] = s;
                }
            }
        }
    }
    __syncthreads();

    // coalesced writeout: 3072 consecutive floats per block
    float* dst = slots + (size_t)blockIdx.x * (256 * NSLOT);
    for (int i = t; i < 256 * NSLOT; i += 256) dst[i] = slotv[i];
}

// One block per row: exact top-m among slot candidates (linear bins), LSE, loss.
__global__ __launch_bounds__(256) void final_kernel(const int* __restrict__ posn,
                                                    const float* __restrict__ posv,
                                                    const int* __restrict__ posi,
                                                    const float* __restrict__ slots,
                                                    int nb,
                                                    float* __restrict__ out, int B) {
    __shared__ unsigned hist[FBINS];
    __shared__ unsigned ssum[256];
    __shared__ float red[256];
    __shared__ float bnd[BNDCAP];
    __shared__ float pv[POSCAP];
    __shared__ int pidx[POSCAP];
    __shared__ int sh_bstar, sh_cumabove, sh_bndn;
    __shared__ float w_bsum, w_ps, w_pe;

    int tid = threadIdx.x;
    int g = blockIdx.x;
    int pn = posn[g];
    int pcap = min(pn, POSCAP);
    int q = min(pn, NEG_K);
    int m = NEG_K - q;
    int ns = nb * NSLOT;

    for (int b = tid; b < FBINS; b += 256) hist[b] = 0u;
    if (tid == 0) {
        sh_bstar = FBINS; sh_cumabove = 0; sh_bndn = 0;
        w_bsum = 0.0f; w_ps = 0.0f; w_pe = 0.0f;
    }
    __syncthreads();

    if (m > 0) {
        for (int j = tid; j < ns; j += 256) {
            int bx = j / NSLOT, k = j - bx * NSLOT;
            float s = slots[(size_t)bx * (256 * NSLOT) + g * NSLOT + k];
            if (s > TSEL) atomicAdd(&hist[fbin(s)], 1u);
        }
    }
    __syncthreads();

    unsigned sum16 = 0;
    int base = tid * (FBINS / 256);
#pragma unroll
    for (int b = 0; b < FBINS / 256; b++) sum16 += hist[base + b];
    ssum[tid] = sum16;
    __syncthreads();
    for (int off = 1; off < 256; off <<= 1) {
        unsigned v = (tid + off < 256) ? ssum[tid + off] : 0u;
        __syncthreads();
        ssum[tid] += v;
        __syncthreads();
    }
    unsigned total = ssum[0];
    unsigned target = (m > 0) ? min(total, (unsigned)m) : 0u;
    if (target > 0) {
        unsigned above = (tid < 255) ? ssum[tid + 1] : 0u;
        if (ssum[tid] >= target && above < target) {
            unsigned cum = above;
            for (int b = base + FBINS / 256 - 1; b >= base; b--) {
                unsigned nc = cum + hist[b];
                if (nc >= target) { sh_bstar = b; sh_cumabove = (int)cum; break; }
                cum = nc;
            }
        }
    }
    __syncthreads();
    int bstar = sh_bstar;
    int cumabove = sh_cumabove;

    float se = 0.0f;
    if (m > 0) {
        for (int j = tid; j < ns; j += 256) {
            int bx = j / NSLOT, k = j - bx * NSLOT;
            float s = slots[(size_t)bx * (256 * NSLOT) + g * NSLOT + k];
            if (s > TSEL) {
                int bin = fbin(s);
                if (bin > bstar) se += expf(s - 20.0f);
                else if (bin == bstar) {
                    int n = atomicAdd(&sh_bndn, 1);
                    if (n < BNDCAP) bnd[n] = s;
                }
            }
        }
    }
    red[tid] = se;
    for (int c = tid; c < pcap; c += 256) {
        pv[c] = posv[g * POSCAP + c];
        pidx[c] = posi[g * POSCAP + c];
    }
    __syncthreads();
    for (int off = 128; off > 0; off >>= 1) {
        if (tid < off) red[tid] += red[tid + off];
        __syncthreads();
    }
    float negexp_above = red[0];
    __syncthreads();

    float psum_p = 0.0f, pexp_p = 0.0f;
    if (pn <= NEG_K) {
        for (int c = tid; c < pcap; c += 256) {
            float v = pv[c];
            psum_p += v;
            pexp_p += expf(v - 20.0f);
        }
    }
    red[tid] = psum_p;
    __syncthreads();
    for (int off = 128; off > 0; off >>= 1) { if (tid < off) red[tid] += red[tid + off]; __syncthreads(); }
    float possum = red[0];
    __syncthreads();
    red[tid] = pexp_p;
    __syncthreads();
    for (int off = 128; off > 0; off >>= 1) { if (tid < off) red[tid] += red[tid + off]; __syncthreads(); }
    float posexp = red[0];
    __syncthreads();

    if (tid < 64) {
        int lane = tid;
        float bsum = 0.0f, ps = 0.0f, pe = 0.0f;
        if (m > 0) {
            int bn = min(sh_bndn, BNDCAP);
            int r = m - cumabove;
            if (r > bn) r = bn;
            for (int it = 0; it < r; it++) {
                float mx = -3.0e38f; int mi = -1;
                for (int c = lane; c < bn; c += 64) {
                    float v = bnd[c];
                    if (v > mx) { mx = v; mi = c; }
                }
#pragma unroll
                for (int off = 32; off > 0; off >>= 1) {
                    float ox = __shfl_xor(mx, off);
                    int oi = __shfl_xor(mi, off);
                    if (ox > mx || (ox == mx && oi >= 0 && (mi < 0 || oi < mi))) { mx = ox; mi = oi; }
                }
                if (lane == 0) {
                    bsum += expf(mx - 20.0f);
                    if (mi >= 0) bnd[mi] = -3.0e38f;
                }
            }
        }
        if (pn > NEG_K) {
            for (int it = 0; it < NEG_K; it++) {
                int mn = 0x7fffffff; int mc = -1;
                for (int c = lane; c < pcap; c += 64) {
                    int ix = pidx[c];
                    if (ix < mn) { mn = ix; mc = c; }
                }
#pragma unroll
                for (int off = 32; off > 0; off >>= 1) {
                    int on = __shfl_xor(mn, off);
                    int oc = __shfl_xor(mc, off);
                    if (on < mn) { mn = on; mc = oc; }
                }
                if (lane == 0 && mc >= 0) {
                    float v = pv[mc];
                    ps += v;
                    pe += expf(v - 20.0f);
                    pidx[mc] = 0x7fffffff;
                }
            }
        }
        if (lane == 0) { w_bsum = bsum; w_ps = ps; w_pe = pe; }
    }
    __syncthreads();

    if (tid == 0) {
        float pos_e = (pn <= NEG_K) ? posexp : w_pe;
        float pos_s = (pn <= NEG_K) ? possum : w_ps;
        float totexp = negexp_above + w_bsum + pos_e;
        float lse = 20.0f + logf(totexp);
        float loss = ((float)q * lse - pos_s) / (float)max(pn, 1);
        atomicAdd(out, loss / (float)B);
    }
}

extern "C" void kernel_launch(void* const* d_in, const int* in_sizes, int n_in,
                              void* d_out, int out_size, void* d_ws, size_t ws_size,
                              hipStream_t stream) {
    const float* F  = (const float*)d_in[0];
    const int* il   = (const int*)d_in[1];
    const float* Pm = (const float*)d_in[2];
    const int* ipi  = (const int*)d_in[3];
    const int* apl  = (const int*)d_in[4];
    float* out = (float*)d_out;

    const int D = 256;
    const int B = in_sizes[0] / D;      // 256
    const int P = in_sizes[2] / D;      // 100000
    const int nb = (P + 63) / 64;       // 1563

    char* ws = (char*)d_ws;
    unsigned short* Fb = (unsigned short*)ws;                 // 128 KiB
    int* batch_lbl = (int*)(ws + 131072);
    int* posn      = (int*)(ws + 131072 + 1024);
    float* posv    = (float*)(ws + 131072 + 4096);
    int* posi      = (int*)(ws + 131072 + 4096 + 256 * POSCAP * 4);
    float* slots   = (float*)(ws + 131072 + 4096 + 2 * 256 * POSCAP * 4);  // nb*256*NSLOT*4 ~ 19.2 MB

    convF_kernel<<<(B * D) / (256 * 8), 256, 0, stream>>>(F, Fb);
    setup_kernel<<<1, 256, 0, stream>>>(il, ipi, apl, B, batch_lbl, posn, out);

    gemm_fused<<<nb, 256, 0, stream>>>(Fb, Pm, apl, batch_lbl,
                                       posn, posv, posi, slots, P);
    final_kernel<<<B, 256, 0, stream>>>(posn, posv, posi, slots, nb, out, B);
}